// Round 3
// baseline (204.982 us; speedup 1.0000x reference)
//
#include <hip/hip_runtime.h>
#include <math.h>

// RG-LRU: B=4, T=4096, W=1024, H=8, BW=128
// Single-pass chained scan. CHUNK=128 (two 64-row halves per block, one stage+barrier),
// full-wave depth-32 look-back: chains are 32 chunks -> ALWAYS one window round trip.
#define NB 4
#define NT 4096
#define NW 1024
#define NH 8
#define CHUNK 128
#define NCH 32          // NT / CHUNK
#define STRIDE_A 136    // bf16 elems per LDS A-row: 272 B = 17*16 (16B-aligned, bank-friendly)

typedef __attribute__((ext_vector_type(8))) short short8;
typedef __attribute__((ext_vector_type(4))) float f32x4;
typedef unsigned long long u64;

__device__ __forceinline__ short bf16rne(float f) {
    unsigned u = __float_as_uint(f);
    u += 0x7fffu + ((u >> 16) & 1u);      // round-to-nearest-even
    return (short)(u >> 16);
}

// ---------------- K0: convert w_in/w_a to frag-major bf16 + NaN-poison AGH ----------
// wfH dst: ((((h*2+g)*4+ks)*8 + ntg)*64 + lane)*8 + jj
// Poisons AGH (1 MiB = 65536 uint4) with NaN: packed (A,H) aggregates are
// self-validating per 64-bit word (atomic 8B store/load; NaN A => unpublished).
__global__ __launch_bounds__(256)
void k0_wfrag(const float* __restrict__ w_in, const float* __restrict__ w_a,
              short* __restrict__ wfH, uint4* __restrict__ poison)
{
    int idx = blockIdx.x * 256 + threadIdx.x;   // over 2*8*128*32 = 65536
    uint4 nv; nv.x = nv.y = nv.z = nv.w = 0xFFFFFFFFu;   // NaN
    poison[idx] = nv;

    int j4 = (idx & 31) * 4;
    int i  = (idx >> 5) & 127;
    int h  = (idx >> 12) & 7;
    int g  = idx >> 15;
    const float* w = g ? w_a : w_in;
    float4 v = *(const float4*)&w[((size_t)h * 128 + i) * 128 + j4];
    const float vf[4] = {v.x, v.y, v.z, v.w};
    const int ks = i >> 5, q = (i >> 3) & 3, jj = i & 7;
    #pragma unroll
    for (int d = 0; d < 4; ++d) {
        int j = j4 + d;
        int lane = q * 16 + (j & 15);
        int ntg = j >> 4;
        size_t dst = ((size_t)(((h * 2 + g) * 4 + ks) * 8 + ntg) * 64 + lane) * 8 + jj;
        wfH[dst] = bf16rne(vf[d]);
    }
}

// ---------------- K: MFMA gates + chunk scan + 1-window look-back + store ----------
// grid (NH, NB*NCH=128), block 512 (8 waves); block tile = 128 t x 128 w (one head).
// Grid linear order monotone in c per (h,b) chain -> with in-order dispatch every
// resident block's predecessors are resident-or-retired (no deadlock at any residency).
// AGH[chain][chunk][col] = packed (float A, float H): h_out = A*h_in + H. NaN = unpublished.
__global__ __launch_bounds__(512, 4)
void k_fused(const float* __restrict__ x, const int* __restrict__ seg,
             const float* __restrict__ a_param,
             const float* __restrict__ b_in, const float* __restrict__ b_a,
             const short* __restrict__ wfH,
             float2* __restrict__ AGH, float* __restrict__ out)
{
    __shared__ short sA[CHUNK * STRIDE_A];   // 34.8 KB

    const int h   = blockIdx.x;
    const int bc  = blockIdx.y;           // b*NCH + c
    const int b   = bc >> 5, c = bc & 31;
    const int tid = threadIdx.x;
    const int wave = tid >> 6, lane = tid & 63;   // wave = n-tile group (0..7)
    const int quad = lane >> 4, m = lane & 15;
    const int row0 = b * NT + c * CHUNK;          // global row into [B*T]

    // ---- stage A: x tile (128 t x 128 k) -> bf16 LDS, one conversion per element ----
    {
        const int r  = tid >> 3;           // 0..63
        const int k0 = (tid & 7) * 16;     // 0,16,..,112
        #pragma unroll
        for (int hh = 0; hh < 2; ++hh) {
            const int rr = r + hh * 64;
            const float4* px = (const float4*)(x + (size_t)(row0 + rr) * NW + h * 128 + k0);
            float4 v0 = px[0], v1 = px[1], v2 = px[2], v3 = px[3];
            const float f[16] = {v0.x, v0.y, v0.z, v0.w, v1.x, v1.y, v1.z, v1.w,
                                 v2.x, v2.y, v2.z, v2.w, v3.x, v3.y, v3.z, v3.w};
            short8 s0, s1;
            #pragma unroll
            for (int j = 0; j < 8; ++j) { s0[j] = bf16rne(f[j]); s1[j] = bf16rne(f[8 + j]); }
            *(short8*)&sA[rr * STRIDE_A + k0]     = s0;
            *(short8*)&sA[rr * STRIDE_A + k0 + 8] = s1;
        }
    }
    __syncthreads();

    // ---- per-column parameters ----
    const int col  = wave * 16 + m;       // 0..127 within head
    const int colg = h * 128 + col;
    const float bi = b_in[colg];
    const float ba = b_a[colg];
    const float c2 = -8.0f * log1pf(expf(a_param[colg]));   // -8*softplus

    // ---- two 64-row halves: MFMA + epilogue + chunk-local scan ----
    float cA = 1.f, cH = 0.f;             // carry across all 8 m-tiles (per column)
    float Pf[8][4], Hf[8][4];             // retained: out = Hf + Pf * h_prev
    #pragma unroll
    for (int hh = 0; hh < 2; ++hh) {
        f32x4 acc[2][4];  // [gate][mt]
        #pragma unroll
        for (int g = 0; g < 2; ++g)
            #pragma unroll
            for (int mt = 0; mt < 4; ++mt)
                acc[g][mt] = (f32x4){0.f, 0.f, 0.f, 0.f};

        #pragma unroll
        for (int ks = 0; ks < 4; ++ks) {
            short8 ah[4];
            #pragma unroll
            for (int mt = 0; mt < 4; ++mt)
                ah[mt] = *(const short8*)&sA[(hh * 64 + mt * 16 + m) * STRIDE_A + ks * 32 + quad * 8];
            #pragma unroll
            for (int g = 0; g < 2; ++g) {
                const size_t fo = ((size_t)(((h * 2 + g) * 4 + ks) * 8 + wave) * 64 + lane) * 8;
                short8 bh = *(const short8*)(wfH + fo);
                #pragma unroll
                for (int mt = 0; mt < 4; ++mt)
                    acc[g][mt] = __builtin_amdgcn_mfma_f32_16x16x32_bf16(ah[mt], bh, acc[g][mt], 0, 0, 0);
            }
        }

        #pragma unroll
        for (int mt = 0; mt < 4; ++mt) {
            float lP[4], lH[4];
            {
                float xv[4]; int sv[4];
                #pragma unroll
                for (int r = 0; r < 4; ++r) {
                    const int rowi = row0 + hh * 64 + mt * 16 + quad * 4 + r;
                    xv[r] = x[(size_t)rowi * NW + colg];
                    sv[r] = seg[rowi];
                }
                #pragma unroll
                for (int r = 0; r < 4; ++r) {
                    const float zx = acc[0][mt][r] + bi;
                    const float za = acc[1][mt][r] + ba;
                    const float gx = __fdividef(1.f, 1.f + __expf(-zx));
                    const float ga = __fdividef(1.f, 1.f + __expf(-za));
                    const float a  = __expf(c2 * ga);
                    const float mult = sqrtf(fmaxf(fmaf(-a, a, 1.f), 0.f));
                    const float av = (sv[r] == 0) ? 0.f : a;
                    const float nx = xv[r] * gx * mult;
                    lP[r] = (r == 0) ? av : lP[r - 1] * av;
                    lH[r] = (r == 0) ? nx : fmaf(av, lH[r - 1], nx);
                }
            }
            // cross-quad inclusive scan of quad totals
            float iA = lP[3], iH = lH[3];
            float uA = __shfl_up(iA, 16), uH = __shfl_up(iH, 16);
            if (quad >= 1) { iH = fmaf(iA, uH, iH); iA = uA * iA; }
            uA = __shfl_up(iA, 32); uH = __shfl_up(iH, 32);
            if (quad >= 2) { iH = fmaf(iA, uH, iH); iA = uA * iA; }
            // exclusive prefix for this quad
            float eA = __shfl_up(iA, 16), eH = __shfl_up(iH, 16);
            if (quad == 0) { eA = 1.f; eH = 0.f; }
            // 16-t tile total (quad 3 inclusive), broadcast per column
            const float mAt = __shfl(iA, 48 + m);
            const float mHt = __shfl(iH, 48 + m);
            // prefix = carry ∘ quad-exclusive; update carry
            const float pA = cA * eA;
            const float pH = fmaf(eA, cH, eH);
            cH = fmaf(mAt, cH, mHt);
            cA = cA * mAt;
            #pragma unroll
            for (int r = 0; r < 4; ++r) {
                Pf[hh * 4 + mt][r] = pA * lP[r];
                Hf[hh * 4 + mt][r] = fmaf(lP[r], pH, lH[r]);
            }
        }
    }
    // NOTE: cA,cH (chunk totals) are replicated across quads for each (wave,m).

    // ---- publish packed aggregate FIRST (successors fold aggregates themselves) ----
    const size_t cb0 = (size_t)(h * NB + b) * NCH * 128;   // chain base (float2 units)
    if (quad == 0) {
        const u64 pk = ((u64)__float_as_uint(cH) << 32) | (u64)__float_as_uint(cA);
        __hip_atomic_store((u64*)&AGH[cb0 + (size_t)c * 128 + col], pk,
                           __ATOMIC_RELAXED, __HIP_MEMORY_SCOPE_AGENT);
    }

    // ---- full-wave depth-32 look-back: ONE window (c <= 31) ----
    // lane (quad q, m) owns predecessor slice {c-1-8q ... c-1-8q-7} of column m's chain,
    // folds it near->far in registers (retry on unpublished), then 4-step ordered shfl
    // composition gives EVERY lane h_prev for its column. No Hi, no broadcast needed.
    float hp = 0.f;
    {
        const int base = c - 1 - quad * 8;
        const int nj   = base < 0 ? 0 : (base >= 7 ? 8 : base + 1);
        float a_ = 1.f, h_ = 0.f;
        if (nj > 0) {
            int folded = 0;
            for (;;) {
                u64 pk[8];
                #pragma unroll
                for (int j = 0; j < 8; ++j) {
                    int idx = base - j; idx = idx < 0 ? 0 : idx;
                    pk[j] = __hip_atomic_load((const u64*)&AGH[cb0 + (size_t)idx * 128 + col],
                                              __ATOMIC_RELAXED, __HIP_MEMORY_SCOPE_AGENT);
                }
                bool stall = false;
                #pragma unroll
                for (int j = 0; j < 8; ++j) {
                    if (j < folded || j >= nj || stall) continue;
                    const float A_ = __uint_as_float((unsigned)pk[j]);
                    if (__builtin_isnan(A_)) { stall = true; continue; }
                    const float H_ = __uint_as_float((unsigned)(pk[j] >> 32));
                    h_ = fmaf(a_, H_, h_);      // fold aggregate near->far
                    a_ *= A_;
                    folded = j + 1;
                }
                if (folded >= nj) break;
                __builtin_amdgcn_s_sleep(1);
            }
        }
        // ordered cross-quad composition (q=0 nearest): hp = final accH
        float accA = 1.f;
        #pragma unroll
        for (int q = 0; q < 4; ++q) {
            const float Aq = __shfl(a_, q * 16 + m);
            const float Hq = __shfl(h_, q * 16 + m);
            hp = fmaf(accA, Hq, hp);
            accA *= Aq;
        }
    }

    // ---- final stores: out = Hf + Pf * h_prev (64B sectors per quad-row) ----
    #pragma unroll
    for (int hh = 0; hh < 2; ++hh)
        #pragma unroll
        for (int mt = 0; mt < 4; ++mt)
            #pragma unroll
            for (int r = 0; r < 4; ++r) {
                const int rowi = row0 + hh * 64 + mt * 16 + quad * 4 + r;
                out[(size_t)rowi * NW + colg] = fmaf(Pf[hh * 4 + mt][r], hp, Hf[hh * 4 + mt][r]);
            }
}

extern "C" void kernel_launch(void* const* d_in, const int* in_sizes, int n_in,
                              void* d_out, int out_size, void* d_ws, size_t ws_size,
                              hipStream_t stream)
{
    (void)in_sizes; (void)n_in; (void)out_size; (void)ws_size;
    const float* x    = (const float*)d_in[0];
    const int*   seg  = (const int*)  d_in[1];
    const float* ap   = (const float*)d_in[2];
    const float* w_in = (const float*)d_in[3];
    const float* b_in = (const float*)d_in[4];
    const float* w_a  = (const float*)d_in[5];
    const float* b_a  = (const float*)d_in[6];
    float* out = (float*)d_out;

    // ws layout (~1.5 MiB): AGH (1 MiB packed aggregates, NaN-poisoned by k0) + wfH (0.5 MiB)
    const size_t NTOP = (size_t)NH * NB * NCH * 128;   // 131072 float2
    float2* AGH = (float2*)d_ws;
    short*  wfH = (short*)(AGH + NTOP);

    k0_wfrag<<<256, 256, 0, stream>>>(w_in, w_a, wfH, (uint4*)AGH);
    dim3 g1(NH, NB * NCH);
    k_fused<<<g1, 512, 0, stream>>>(x, seg, ap, b_in, b_a, wfH, AGH, out);
}

// Round 4
// 175.186 us; speedup vs baseline: 1.1701x; 1.1701x over previous
//
#include <hip/hip_runtime.h>
#include <math.h>

// RG-LRU: B=4, T=4096, W=1024, H=8, BW=128
// Single-pass chained scan, CHUNK=64 (register-fit retention, no spill).
// Full-wave depth-64 look-back: <=2 windows of 32 preds, each ONE memory round trip.
#define NB 4
#define NT 4096
#define NW 1024
#define NH 8
#define CHUNK 64
#define NCH 64          // NT / CHUNK
#define STRIDE_A 136    // bf16 elems per LDS A-row: 272 B = 17*16 (16B-aligned, bank-friendly)

typedef __attribute__((ext_vector_type(8))) short short8;
typedef __attribute__((ext_vector_type(4))) float f32x4;
typedef unsigned long long u64;

__device__ __forceinline__ short bf16rne(float f) {
    unsigned u = __float_as_uint(f);
    u += 0x7fffu + ((u >> 16) & 1u);      // round-to-nearest-even
    return (short)(u >> 16);
}

// ---------------- K0: convert w_in/w_a to frag-major bf16 + NaN-poison AGH ----------
// wfH dst: ((((h*2+g)*4+ks)*8 + ntg)*64 + lane)*8 + jj
// Poisons AGH (2 MiB = 131072 uint4) with NaN: packed (A,H) aggregates are
// self-validating per 64-bit word (atomic 8B store/load; NaN A => unpublished).
__global__ __launch_bounds__(256)
void k0_wfrag(const float* __restrict__ w_in, const float* __restrict__ w_a,
              short* __restrict__ wfH, uint4* __restrict__ poison)
{
    int idx = blockIdx.x * 256 + threadIdx.x;   // over 2*8*128*32 = 65536
    uint4 nv; nv.x = nv.y = nv.z = nv.w = 0xFFFFFFFFu;   // NaN
    poison[idx]         = nv;
    poison[idx + 65536] = nv;

    int j4 = (idx & 31) * 4;
    int i  = (idx >> 5) & 127;
    int h  = (idx >> 12) & 7;
    int g  = idx >> 15;
    const float* w = g ? w_a : w_in;
    float4 v = *(const float4*)&w[((size_t)h * 128 + i) * 128 + j4];
    const float vf[4] = {v.x, v.y, v.z, v.w};
    const int ks = i >> 5, q = (i >> 3) & 3, jj = i & 7;
    #pragma unroll
    for (int d = 0; d < 4; ++d) {
        int j = j4 + d;
        int lane = q * 16 + (j & 15);
        int ntg = j >> 4;
        size_t dst = ((size_t)(((h * 2 + g) * 4 + ks) * 8 + ntg) * 64 + lane) * 8 + jj;
        wfH[dst] = bf16rne(vf[d]);
    }
}

// ---------------- K: MFMA gates + chunk scan + full-wave look-back + store ----------
// grid (NH, NB*NCH=256), block 512 (8 waves); block tile = 64 t x 128 w (one head).
// Grid linear order monotone in c per (h,b) chain -> with in-order dispatch every
// resident block's predecessors are resident-or-retired (no deadlock at any residency).
// AGH[chain][chunk][col] = packed (float A, float H): h_out = A*h_in + H. NaN = unpublished.
// EVERY chunk publishes its aggregate right after compute (before its own look-back),
// so aggregates appear at compute-finish time with zero serial chaining.
__global__ __launch_bounds__(512)
void k_fused(const float* __restrict__ x, const int* __restrict__ seg,
             const float* __restrict__ a_param,
             const float* __restrict__ b_in, const float* __restrict__ b_a,
             const short* __restrict__ wfH,
             float2* __restrict__ AGH, float* __restrict__ out)
{
    __shared__ short sA[CHUNK * STRIDE_A];   // 17.4 KB

    const int h   = blockIdx.x;
    const int bc  = blockIdx.y;           // b*NCH + c
    const int b   = bc >> 6, c = bc & 63;
    const int tid = threadIdx.x;
    const int wave = tid >> 6, lane = tid & 63;   // wave = n-tile group (0..7)
    const int quad = lane >> 4, m = lane & 15;
    const int row0 = b * NT + c * CHUNK;          // global row into [B*T]

    // ---- stage A: x tile (64 t x 128 k) -> bf16 LDS, one conversion per element ----
    {
        const int r  = tid >> 3;           // 0..63
        const int k0 = (tid & 7) * 16;     // 0,16,..,112
        const float4* px = (const float4*)(x + (size_t)(row0 + r) * NW + h * 128 + k0);
        float4 v0 = px[0], v1 = px[1], v2 = px[2], v3 = px[3];
        const float f[16] = {v0.x, v0.y, v0.z, v0.w, v1.x, v1.y, v1.z, v1.w,
                             v2.x, v2.y, v2.z, v2.w, v3.x, v3.y, v3.z, v3.w};
        short8 s0, s1;
        #pragma unroll
        for (int j = 0; j < 8; ++j) { s0[j] = bf16rne(f[j]); s1[j] = bf16rne(f[8 + j]); }
        *(short8*)&sA[r * STRIDE_A + k0]     = s0;
        *(short8*)&sA[r * STRIDE_A + k0 + 8] = s1;
    }
    __syncthreads();

    // ---- MFMA main loop over K (A from LDS, B frags from L2-resident wfH) ----
    f32x4 acc[2][4];  // [gate][mt]
    #pragma unroll
    for (int g = 0; g < 2; ++g)
        #pragma unroll
        for (int mt = 0; mt < 4; ++mt)
            acc[g][mt] = (f32x4){0.f, 0.f, 0.f, 0.f};

    #pragma unroll
    for (int ks = 0; ks < 4; ++ks) {
        short8 ah[4];
        #pragma unroll
        for (int mt = 0; mt < 4; ++mt)
            ah[mt] = *(const short8*)&sA[(mt * 16 + m) * STRIDE_A + ks * 32 + quad * 8];
        #pragma unroll
        for (int g = 0; g < 2; ++g) {
            const size_t fo = ((size_t)(((h * 2 + g) * 4 + ks) * 8 + wave) * 64 + lane) * 8;
            short8 bh = *(const short8*)(wfH + fo);
            #pragma unroll
            for (int mt = 0; mt < 4; ++mt)
                acc[g][mt] = __builtin_amdgcn_mfma_f32_16x16x32_bf16(ah[mt], bh, acc[g][mt], 0, 0, 0);
        }
    }

    // ---- per-column parameters ----
    const int col  = wave * 16 + m;       // 0..127 within head
    const int colg = h * 128 + col;
    const float bi = b_in[colg];
    const float ba = b_a[colg];
    const float c2 = -8.0f * log1pf(expf(a_param[colg]));   // -8*softplus

    // ---- epilogue + chunk-local scan (C layout: row = quad*4+reg, col = lane&15) ----
    float cA = 1.f, cH = 0.f;             // carry across m-tiles (per column)
    float Pf[4][4], Hf[4][4];             // retained: out = Hf + Pf * h_prev
    #pragma unroll
    for (int mt = 0; mt < 4; ++mt) {
        float lP[4], lH[4];
        {
            float xv[4]; int sv[4];
            #pragma unroll
            for (int r = 0; r < 4; ++r) {
                const int rowi = row0 + mt * 16 + quad * 4 + r;
                xv[r] = x[(size_t)rowi * NW + colg];
                sv[r] = seg[rowi];
            }
            #pragma unroll
            for (int r = 0; r < 4; ++r) {
                const float zx = acc[0][mt][r] + bi;
                const float za = acc[1][mt][r] + ba;
                const float gx = __fdividef(1.f, 1.f + __expf(-zx));
                const float ga = __fdividef(1.f, 1.f + __expf(-za));
                const float a  = __expf(c2 * ga);
                const float mult = sqrtf(fmaxf(fmaf(-a, a, 1.f), 0.f));
                const float av = (sv[r] == 0) ? 0.f : a;
                const float nx = xv[r] * gx * mult;
                lP[r] = (r == 0) ? av : lP[r - 1] * av;
                lH[r] = (r == 0) ? nx : fmaf(av, lH[r - 1], nx);
            }
        }
        // cross-quad inclusive scan of quad totals
        float iA = lP[3], iH = lH[3];
        float uA = __shfl_up(iA, 16), uH = __shfl_up(iH, 16);
        if (quad >= 1) { iH = fmaf(iA, uH, iH); iA = uA * iA; }
        uA = __shfl_up(iA, 32); uH = __shfl_up(iH, 32);
        if (quad >= 2) { iH = fmaf(iA, uH, iH); iA = uA * iA; }
        // exclusive prefix for this quad
        float eA = __shfl_up(iA, 16), eH = __shfl_up(iH, 16);
        if (quad == 0) { eA = 1.f; eH = 0.f; }
        // 16-t tile total (quad 3 inclusive), broadcast per column
        const float mAt = __shfl(iA, 48 + m);
        const float mHt = __shfl(iH, 48 + m);
        // prefix = carry ∘ quad-exclusive; update carry
        const float pA = cA * eA;
        const float pH = fmaf(eA, cH, eH);
        cH = fmaf(mAt, cH, mHt);
        cA = cA * mAt;
        #pragma unroll
        for (int r = 0; r < 4; ++r) {
            Pf[mt][r] = pA * lP[r];
            Hf[mt][r] = fmaf(lP[r], pH, lH[r]);
        }
    }
    // NOTE: cA,cH (chunk totals) are replicated across quads for each (wave,m).

    // ---- publish packed aggregate FIRST (zero serial chaining between blocks) ----
    const size_t cb0 = (size_t)(h * NB + b) * NCH * 128;   // chain base (float2 units)
    if (quad == 0) {
        const u64 pk = ((u64)__float_as_uint(cH) << 32) | (u64)__float_as_uint(cA);
        __hip_atomic_store((u64*)&AGH[cb0 + (size_t)c * 128 + col], pk,
                           __ATOMIC_RELAXED, __HIP_MEMORY_SCOPE_AGENT);
    }

    // ---- full-wave look-back: <=2 windows of 32 predecessors, 1 round trip each ----
    // Window w: lane (quad q, m) owns preds {c-1-32w-8q-j, j=0..7} of column m's chain,
    // folds them near->far in registers (retry on unpublished), then ordered 4-step
    // shfl composition; windows compose via running (accA, hp). All lanes get h_prev.
    float hp = 0.f;
    {
        float accA = 1.f;
        const int nw = (c + 31) >> 5;       // windows needed (0 for c==0)
        for (int w = 0; w < nw; ++w) {
            const int base = c - 1 - (w * 32 + quad * 8);
            const int nj   = base < 0 ? 0 : (base >= 7 ? 8 : base + 1);
            float a_ = 1.f, h_ = 0.f;
            if (nj > 0) {
                int folded = 0;
                for (;;) {
                    u64 pk[8];
                    #pragma unroll
                    for (int j = 0; j < 8; ++j) {
                        int idx = base - j; idx = idx < 0 ? 0 : idx;
                        pk[j] = __hip_atomic_load((const u64*)&AGH[cb0 + (size_t)idx * 128 + col],
                                                  __ATOMIC_RELAXED, __HIP_MEMORY_SCOPE_AGENT);
                    }
                    bool stall = false;
                    #pragma unroll
                    for (int j = 0; j < 8; ++j) {
                        if (j < folded || j >= nj || stall) continue;
                        const float A_ = __uint_as_float((unsigned)pk[j]);
                        if (__builtin_isnan(A_)) { stall = true; continue; }
                        const float H_ = __uint_as_float((unsigned)(pk[j] >> 32));
                        h_ = fmaf(a_, H_, h_);      // fold aggregate near->far
                        a_ *= A_;
                        folded = j + 1;
                    }
                    if (folded >= nj) break;
                    __builtin_amdgcn_s_sleep(1);
                }
            }
            // ordered cross-quad composition (q=0 nearest)
            #pragma unroll
            for (int q = 0; q < 4; ++q) {
                const float Aq = __shfl(a_, q * 16 + m);
                const float Hq = __shfl(h_, q * 16 + m);
                hp = fmaf(accA, Hq, hp);
                accA *= Aq;
            }
        }
    }

    // ---- final stores: out = Hf + Pf * h_prev (64B sectors per quad-row) ----
    #pragma unroll
    for (int mt = 0; mt < 4; ++mt) {
        #pragma unroll
        for (int r = 0; r < 4; ++r) {
            const int rowi = row0 + mt * 16 + quad * 4 + r;
            out[(size_t)rowi * NW + colg] = fmaf(Pf[mt][r], hp, Hf[mt][r]);
        }
    }
}

extern "C" void kernel_launch(void* const* d_in, const int* in_sizes, int n_in,
                              void* d_out, int out_size, void* d_ws, size_t ws_size,
                              hipStream_t stream)
{
    (void)in_sizes; (void)n_in; (void)out_size; (void)ws_size;
    const float* x    = (const float*)d_in[0];
    const int*   seg  = (const int*)  d_in[1];
    const float* ap   = (const float*)d_in[2];
    const float* w_in = (const float*)d_in[3];
    const float* b_in = (const float*)d_in[4];
    const float* w_a  = (const float*)d_in[5];
    const float* b_a  = (const float*)d_in[6];
    float* out = (float*)d_out;

    // ws layout (~2.5 MiB): AGH (2 MiB packed aggregates, NaN-poisoned by k0) + wfH (0.5 MiB)
    const size_t NTOP = (size_t)NH * NB * NCH * 128;   // 262144 float2
    float2* AGH = (float2*)d_ws;
    short*  wfH = (short*)(AGH + NTOP);

    k0_wfrag<<<256, 256, 0, stream>>>(w_in, w_a, wfH, (uint4*)AGH);
    dim3 g1(NH, NB * NCH);
    k_fused<<<g1, 512, 0, stream>>>(x, seg, ap, b_in, b_a, wfH, AGH, out);
}

// Round 5
// 163.813 us; speedup vs baseline: 1.2513x; 1.0694x over previous
//
#include <hip/hip_runtime.h>
#include <math.h>

// RG-LRU: B=4, T=4096, W=1024, H=8, BW=128
// Single-pass chained scan, CHUNK=64. Packed (A,H) aggregates, publish-first.
// Full-wave look-back: windows of 16 preds (pk[4]/lane, 8 VGPR) -> <=4 round trips.
#define NB 4
#define NT 4096
#define NW 1024
#define NH 8
#define CHUNK 64
#define NCH 64          // NT / CHUNK
#define STRIDE_A 136    // bf16 elems per LDS A-row: 272 B = 17*16 (16B-aligned, bank-friendly)

typedef __attribute__((ext_vector_type(8))) short short8;
typedef __attribute__((ext_vector_type(4))) float f32x4;
typedef unsigned long long u64;

__device__ __forceinline__ short bf16rne(float f) {
    unsigned u = __float_as_uint(f);
    u += 0x7fffu + ((u >> 16) & 1u);      // round-to-nearest-even
    return (short)(u >> 16);
}

// ---------------- K0: convert w_in/w_a to frag-major bf16 + NaN-poison AGH ----------
// wfH dst: ((((h*2+g)*4+ks)*8 + ntg)*64 + lane)*8 + jj
// Poisons AGH (2 MiB = 131072 uint4) with NaN: packed (A,H) aggregates are
// self-validating per 64-bit word (atomic 8B store/load; NaN A => unpublished).
__global__ __launch_bounds__(256)
void k0_wfrag(const float* __restrict__ w_in, const float* __restrict__ w_a,
              short* __restrict__ wfH, uint4* __restrict__ poison)
{
    int idx = blockIdx.x * 256 + threadIdx.x;   // over 2*8*128*32 = 65536
    uint4 nv; nv.x = nv.y = nv.z = nv.w = 0xFFFFFFFFu;   // NaN
    poison[idx]         = nv;
    poison[idx + 65536] = nv;

    int j4 = (idx & 31) * 4;
    int i  = (idx >> 5) & 127;
    int h  = (idx >> 12) & 7;
    int g  = idx >> 15;
    const float* w = g ? w_a : w_in;
    float4 v = *(const float4*)&w[((size_t)h * 128 + i) * 128 + j4];
    const float vf[4] = {v.x, v.y, v.z, v.w};
    const int ks = i >> 5, q = (i >> 3) & 3, jj = i & 7;
    #pragma unroll
    for (int d = 0; d < 4; ++d) {
        int j = j4 + d;
        int lane = q * 16 + (j & 15);
        int ntg = j >> 4;
        size_t dst = ((size_t)(((h * 2 + g) * 4 + ks) * 8 + ntg) * 64 + lane) * 8 + jj;
        wfH[dst] = bf16rne(vf[d]);
    }
}

// ---------------- K: MFMA gates + chunk scan + full-wave look-back + store ----------
// grid (NH, NB*NCH=256), block 512 (8 waves); block tile = 64 t x 128 w (one head).
// Grid linear order monotone in c per (h,b) chain -> with in-order dispatch every
// resident block's predecessors are resident-or-retired (no deadlock at any residency).
// AGH[chain][chunk][col] = packed (float A, float H): h_out = A*h_in + H. NaN = unpublished.
// EVERY chunk publishes its aggregate right after compute (before its own look-back),
// so aggregates appear at compute-finish time with zero serial chaining.
__global__ __launch_bounds__(512)
void k_fused(const float* __restrict__ x, const int* __restrict__ seg,
             const float* __restrict__ a_param,
             const float* __restrict__ b_in, const float* __restrict__ b_a,
             const short* __restrict__ wfH,
             float2* __restrict__ AGH, float* __restrict__ out)
{
    __shared__ short sA[CHUNK * STRIDE_A];   // 17.4 KB
    __shared__ int   sSeg[CHUNK];            // 256 B (seg tile, broadcast reads)

    const int h   = blockIdx.x;
    const int bc  = blockIdx.y;           // b*NCH + c
    const int b   = bc >> 6, c = bc & 63;
    const int tid = threadIdx.x;
    const int wave = tid >> 6, lane = tid & 63;   // wave = n-tile group (0..7)
    const int quad = lane >> 4, m = lane & 15;
    const int row0 = b * NT + c * CHUNK;          // global row into [B*T]

    // ---- stage A: x tile (64 t x 128 k) -> bf16 LDS, one conversion per element ----
    {
        const int r  = tid >> 3;           // 0..63
        const int k0 = (tid & 7) * 16;     // 0,16,..,112
        const float4* px = (const float4*)(x + (size_t)(row0 + r) * NW + h * 128 + k0);
        float4 v0 = px[0], v1 = px[1], v2 = px[2], v3 = px[3];
        const float f[16] = {v0.x, v0.y, v0.z, v0.w, v1.x, v1.y, v1.z, v1.w,
                             v2.x, v2.y, v2.z, v2.w, v3.x, v3.y, v3.z, v3.w};
        short8 s0, s1;
        #pragma unroll
        for (int j = 0; j < 8; ++j) { s0[j] = bf16rne(f[j]); s1[j] = bf16rne(f[8 + j]); }
        *(short8*)&sA[r * STRIDE_A + k0]     = s0;
        *(short8*)&sA[r * STRIDE_A + k0 + 8] = s1;
        if ((tid & 7) == 0) sSeg[r] = seg[row0 + r];
    }
    __syncthreads();

    // ---- MFMA main loop over K (A from LDS, B frags from L2-resident wfH) ----
    f32x4 acc[2][4];  // [gate][mt]
    #pragma unroll
    for (int g = 0; g < 2; ++g)
        #pragma unroll
        for (int mt = 0; mt < 4; ++mt)
            acc[g][mt] = (f32x4){0.f, 0.f, 0.f, 0.f};

    #pragma unroll
    for (int ks = 0; ks < 4; ++ks) {
        short8 ah[4];
        #pragma unroll
        for (int mt = 0; mt < 4; ++mt)
            ah[mt] = *(const short8*)&sA[(mt * 16 + m) * STRIDE_A + ks * 32 + quad * 8];
        #pragma unroll
        for (int g = 0; g < 2; ++g) {
            const size_t fo = ((size_t)(((h * 2 + g) * 4 + ks) * 8 + wave) * 64 + lane) * 8;
            short8 bh = *(const short8*)(wfH + fo);
            #pragma unroll
            for (int mt = 0; mt < 4; ++mt)
                acc[g][mt] = __builtin_amdgcn_mfma_f32_16x16x32_bf16(ah[mt], bh, acc[g][mt], 0, 0, 0);
        }
    }

    // ---- per-column parameters ----
    const int col  = wave * 16 + m;       // 0..127 within head
    const int colg = h * 128 + col;
    const float bi = b_in[colg];
    const float ba = b_a[colg];
    const float c2 = -8.0f * log1pf(expf(a_param[colg]));   // -8*softplus

    // ---- epilogue + chunk-local scan (C layout: row = quad*4+reg, col = lane&15) ----
    float cA = 1.f, cH = 0.f;             // carry across m-tiles (per column)
    float Pf[4][4], Hf[4][4];             // retained: out = Hf + Pf * h_prev
    #pragma unroll
    for (int mt = 0; mt < 4; ++mt) {
        float lP[4], lH[4];
        {
            float xv[4];
            #pragma unroll
            for (int r = 0; r < 4; ++r) {
                const int rowi = row0 + mt * 16 + quad * 4 + r;
                xv[r] = x[(size_t)rowi * NW + colg];
            }
            const int4 sv4 = *(const int4*)&sSeg[mt * 16 + quad * 4];
            const int sv[4] = {sv4.x, sv4.y, sv4.z, sv4.w};
            #pragma unroll
            for (int r = 0; r < 4; ++r) {
                const float zx = acc[0][mt][r] + bi;
                const float za = acc[1][mt][r] + ba;
                const float gx = __fdividef(1.f, 1.f + __expf(-zx));
                const float ga = __fdividef(1.f, 1.f + __expf(-za));
                const float a  = __expf(c2 * ga);
                const float mult = sqrtf(fmaxf(fmaf(-a, a, 1.f), 0.f));
                const float av = (sv[r] == 0) ? 0.f : a;
                const float nx = xv[r] * gx * mult;
                lP[r] = (r == 0) ? av : lP[r - 1] * av;
                lH[r] = (r == 0) ? nx : fmaf(av, lH[r - 1], nx);
            }
        }
        // cross-quad inclusive scan of quad totals
        float iA = lP[3], iH = lH[3];
        float uA = __shfl_up(iA, 16), uH = __shfl_up(iH, 16);
        if (quad >= 1) { iH = fmaf(iA, uH, iH); iA = uA * iA; }
        uA = __shfl_up(iA, 32); uH = __shfl_up(iH, 32);
        if (quad >= 2) { iH = fmaf(iA, uH, iH); iA = uA * iA; }
        // exclusive prefix for this quad
        float eA = __shfl_up(iA, 16), eH = __shfl_up(iH, 16);
        if (quad == 0) { eA = 1.f; eH = 0.f; }
        // 16-t tile total (quad 3 inclusive), broadcast per column
        const float mAt = __shfl(iA, 48 + m);
        const float mHt = __shfl(iH, 48 + m);
        // prefix = carry ∘ quad-exclusive; update carry
        const float pA = cA * eA;
        const float pH = fmaf(eA, cH, eH);
        cH = fmaf(mAt, cH, mHt);
        cA = cA * mAt;
        #pragma unroll
        for (int r = 0; r < 4; ++r) {
            Pf[mt][r] = pA * lP[r];
            Hf[mt][r] = fmaf(lP[r], pH, lH[r]);
        }
    }
    // NOTE: cA,cH (chunk totals) are replicated across quads for each (wave,m).

    // ---- publish packed aggregate FIRST (zero serial chaining between blocks) ----
    const size_t cb0 = (size_t)(h * NB + b) * NCH * 128;   // chain base (float2 units)
    if (quad == 0) {
        const u64 pk = ((u64)__float_as_uint(cH) << 32) | (u64)__float_as_uint(cA);
        __hip_atomic_store((u64*)&AGH[cb0 + (size_t)c * 128 + col], pk,
                           __ATOMIC_RELAXED, __HIP_MEMORY_SCOPE_AGENT);
    }

    // ---- full-wave look-back: windows of 16 predecessors, 1 round trip each ----
    // Window w: lane (quad q, m) owns preds {c-1-16w-4q-j, j=0..3} of column m's chain,
    // folds them near->far in registers (retry on unpublished), then ordered 4-step
    // shfl composition; windows compose via running (accA, hp). All lanes get h_prev.
    float hp = 0.f;
    {
        float accA = 1.f;
        const int nw = (c + 15) >> 4;       // windows needed (0 for c==0)
        for (int w = 0; w < nw; ++w) {
            const int base = c - 1 - (w * 16 + quad * 4);
            const int nj   = base < 0 ? 0 : (base >= 3 ? 4 : base + 1);
            float a_ = 1.f, h_ = 0.f;
            if (nj > 0) {
                int folded = 0;
                for (;;) {
                    u64 pk[4];
                    #pragma unroll
                    for (int j = 0; j < 4; ++j) {
                        int idx = base - j; idx = idx < 0 ? 0 : idx;
                        pk[j] = __hip_atomic_load((const u64*)&AGH[cb0 + (size_t)idx * 128 + col],
                                                  __ATOMIC_RELAXED, __HIP_MEMORY_SCOPE_AGENT);
                    }
                    bool stall = false;
                    #pragma unroll
                    for (int j = 0; j < 4; ++j) {
                        if (j < folded || j >= nj || stall) continue;
                        const float A_ = __uint_as_float((unsigned)pk[j]);
                        if (__builtin_isnan(A_)) { stall = true; continue; }
                        const float H_ = __uint_as_float((unsigned)(pk[j] >> 32));
                        h_ = fmaf(a_, H_, h_);      // fold aggregate near->far
                        a_ *= A_;
                        folded = j + 1;
                    }
                    if (folded >= nj) break;
                    __builtin_amdgcn_s_sleep(4);
                }
            }
            // ordered cross-quad composition (q=0 nearest)
            #pragma unroll
            for (int q = 0; q < 4; ++q) {
                const float Aq = __shfl(a_, q * 16 + m);
                const float Hq = __shfl(h_, q * 16 + m);
                hp = fmaf(accA, Hq, hp);
                accA *= Aq;
            }
        }
    }

    // ---- final stores: out = Hf + Pf * h_prev (64B sectors per quad-row) ----
    #pragma unroll
    for (int mt = 0; mt < 4; ++mt) {
        #pragma unroll
        for (int r = 0; r < 4; ++r) {
            const int rowi = row0 + mt * 16 + quad * 4 + r;
            out[(size_t)rowi * NW + colg] = fmaf(Pf[mt][r], hp, Hf[mt][r]);
        }
    }
}

extern "C" void kernel_launch(void* const* d_in, const int* in_sizes, int n_in,
                              void* d_out, int out_size, void* d_ws, size_t ws_size,
                              hipStream_t stream)
{
    (void)in_sizes; (void)n_in; (void)out_size; (void)ws_size;
    const float* x    = (const float*)d_in[0];
    const int*   seg  = (const int*)  d_in[1];
    const float* ap   = (const float*)d_in[2];
    const float* w_in = (const float*)d_in[3];
    const float* b_in = (const float*)d_in[4];
    const float* w_a  = (const float*)d_in[5];
    const float* b_a  = (const float*)d_in[6];
    float* out = (float*)d_out;

    // ws layout (~2.5 MiB): AGH (2 MiB packed aggregates, NaN-poisoned by k0) + wfH (0.5 MiB)
    const size_t NTOP = (size_t)NH * NB * NCH * 128;   // 262144 float2
    float2* AGH = (float2*)d_ws;
    short*  wfH = (short*)(AGH + NTOP);

    k0_wfrag<<<256, 256, 0, stream>>>(w_in, w_a, wfH, (uint4*)AGH);
    dim3 g1(NH, NB * NCH);
    k_fused<<<g1, 512, 0, stream>>>(x, seg, ap, b_in, b_a, wfH, AGH, out);
}